// Round 7
// baseline (48.755 us; speedup 1.0000x reference)
//
#include <hip/hip_runtime.h>

// IAF spiking layer: data (B*T, F) fp32, B=32, T=1024, F=1024.
// One thread per (b,f) chain; t sequential; 512 waves (2/CU).
//
// R6 theory: we are WRITE-BW-bound (131 MB / 44.6us = 2.94 TB/s ~ 93% of the
// per-direction rate implied by the 6.29 TB/s copy ceiling). Input+output =
// 268 MB > 256 MB L3 -> self-thrash: output dirty lines evict between graph
// replays (WRITE_SIZE = full 131 MB/dispatch), input half-resident (FETCH =
// 65 MB). Fix: NON-TEMPORAL INPUT LOADS (aux=2 = NT cpol bit on
// global_load_lds) so reads don't allocate in L3; the 134 MB output then
// fits L3 entirely, replays hit their own dirty lines, HBM writes -> ~0.
// Stores stay PLAIN (they must allocate). NT is a hint: correctness-neutral.
//
// Skeleton = R1 (best, 44.6us): depth-3 issue-first global_load_lds pipeline,
// counted vmcnt (never 0 mid-loop), batched xv preload, scalar coalesced
// stores. Inner math = R5's proven bit-exact shortened chain.
// Encoded lessons: transpose+wide stores = overhead (R3/R4); wave
// specialization no gain (R5); nt on STORES is a no-op (R2).

constexpr int T = 1024;
constexpr int F = 1024;
constexpr int DEPTH = 16;                 // t-steps per chunk
constexpr int NC = T / DEPTH;             // 64 chunks
constexpr int CHUNK_FLOATS = DEPTH * 64;  // 4 KB per ring buffer

#define WAITVM(N) asm volatile("s_waitcnt vmcnt(" #N ")" ::: "memory")

__global__ __launch_bounds__(64) void iaf_kernel(const float* __restrict__ x,
                                                 float* __restrict__ out) {
    __shared__ float lds[4 * CHUNK_FLOATS];   // 16 KB ring (4 buffers)

    const int lane = threadIdx.x;             // 0..63
    const int b = blockIdx.x >> 4;            // 32 batch rows
    const int f0 = (blockIdx.x & 15) * 64;    // feature block base

    const size_t base = ((size_t)b * T) * F + f0;
    const float* __restrict__ p = x + base;   // row t at p + t*F
    float* __restrict__ q = out + base + lane;

    // global_load_lds lane map (verified R1-R5, absmax 0): instr r of chunk k
    // covers global row k*16 + r*4 + (lane>>4), floats f0+(lane&15)*4..+3;
    // LDS dest linear == row-major [16][64] float tile.
    const int lrow = lane >> 4;
    const int lcol = (lane & 15) * 4;

    float s = 0.0f, a = 0.0f;

    auto issue_chunk = [&](int k) {
        float* lb = &lds[(k & 3) * CHUNK_FLOATS];
#pragma unroll
        for (int r = 0; r < 4; ++r) {
            const float* gsrc = p + (size_t)(k * DEPTH + r * 4 + lrow) * F + lcol;
            __builtin_amdgcn_global_load_lds(
                (const __attribute__((address_space(1))) void*)gsrc,
                (__attribute__((address_space(3))) void*)(lb + r * 256),
                16, 0, /*aux=NT*/ 2);
        }
        __builtin_amdgcn_sched_barrier(0);   // pin issue order for vmcnt math
    };

    auto compute_chunk = [&](int k) {
        const float* lb = &lds[(k & 3) * CHUNK_FLOATS];
        float xv[DEPTH];                     // banks lane%32, 2-way (free)
#pragma unroll
        for (int i = 0; i < DEPTH; ++i) xv[i] = lb[i * 64 + lane];
#pragma unroll
        for (int i = 0; i < DEPTH; ++i) {
            // bit-exact reference semantics (validated absmax 0 in R5):
            //   s1 = (x + s) - a;  t2 = s1 + 1
            //   s  = max(t2,0) - 1                  (relu clamp, exact order)
            //   a  = floor(max(t2,1) - 1)  == (s>0 ? floor(s) : 0)
            const float s1 = (xv[i] + s) - a;
            const float t2 = s1 + 1.0f;
            s = fmaxf(t2, 0.0f) - 1.0f;
            a = floorf(fmaxf(t2, 1.0f) - 1.0f);
            q[(size_t)(k * DEPTH + i) * F] = a;   // plain store: allocate L3
        }
        __builtin_amdgcn_sched_barrier(0);
    };

    // prologue: 3 chunks in flight (R1-proven schedule)
    issue_chunk(0);
    issue_chunk(1);
    issue_chunk(2);

    WAITVM(8);  issue_chunk(3); compute_chunk(0);
    WAITVM(24); issue_chunk(4); compute_chunk(1);
    WAITVM(40); issue_chunk(5); compute_chunk(2);

    // steady: ops after L(c) = 3*16 stores + 2*4 loads = 56; max in-flight 60
    for (int c = 3; c <= 61; ++c) {
        WAITVM(56);
        if (c <= 60) issue_chunk(c + 3);
        compute_chunk(c);
    }

    WAITVM(48); compute_chunk(62);
    WAITVM(48); compute_chunk(63);
}

extern "C" void kernel_launch(void* const* d_in, const int* in_sizes, int n_in,
                              void* d_out, int out_size, void* d_ws, size_t ws_size,
                              hipStream_t stream) {
    const float* x = (const float*)d_in[0];
    float* out = (float*)d_out;
    // 512 blocks x 64 threads = 32768 chains; LDS 16 KB; 2 blocks/CU.
    iaf_kernel<<<dim3(512), dim3(64), 0, stream>>>(x, out);
}